// Round 1
// baseline (1612.107 us; speedup 1.0000x reference)
//
#include <hip/hip_runtime.h>
#include <hip/hip_bf16.h>

// Gaussian Attention, fp32 reference-exact decomposition:
//   K1 proj:    xq = xsa@Wq^T, xkb = xsa@Wk^T + biasW.T   -> layout (b,k,l,d)
//   K2 kn:      kn[b,k,l] = sum_d xkb^2
//   K3 attn:    flash: P = softmax_j((2*Q.Kb^T - kn_j)/16); ybar = P @ xsa
//               (qn_i row-constant dropped -- exact under softmax)
//   K4 combine: out[b,i,k*E+f] = ybar[b,k,i] @ Wv3[k] + bias2W[f,k]
//
// Workspace (floats): xq 4M | xkb 4M | kn 16K | ybar 8M  => 64.1 MiB

#define L_ 2048
#define E_ 512
#define KE_ 256
#define NH_ 4   // heads K

// ---------------- K1: projection GEMM (M=4096, N=2048, K=512) ----------------
__global__ __launch_bounds__(256) void proj_kernel(
    const float* __restrict__ xsa, const float* __restrict__ Wq,
    const float* __restrict__ Wk, const float* __restrict__ biasW,
    float* __restrict__ xq, float* __restrict__ xkb)
{
    __shared__ float Ast[32][132];   // k-major A tile (128 m)
    __shared__ float Bst[32][132];   // k-major B tile (128 n)
    const int t = threadIdx.x;
    const int m0 = blockIdx.x * 128;            // 0..4095
    const int n0 = blockIdx.y * 128;            // 0..2047
    const bool isK = (n0 >= 1024);
    const float* W = isK ? Wk : Wq;
    const int nW0 = isK ? (n0 - 1024) : n0;
    const int ty = t >> 4, tx = t & 15;

    float acc[8][8];
#pragma unroll
    for (int i = 0; i < 8; i++)
#pragma unroll
        for (int j = 0; j < 8; j++) acc[i][j] = 0.f;

    for (int kk0 = 0; kk0 < 512; kk0 += 32) {
#pragma unroll
        for (int r = 0; r < 4; r++) {
            int idx = t + r * 256;      // 0..1023
            int row = idx >> 3;         // 0..127
            int c4  = idx & 7;          // 0..7
            float4 v = *reinterpret_cast<const float4*>(&xsa[(size_t)(m0 + row) * 512 + kk0 + c4 * 4]);
            Ast[c4*4+0][row] = v.x; Ast[c4*4+1][row] = v.y;
            Ast[c4*4+2][row] = v.z; Ast[c4*4+3][row] = v.w;
            float4 w = *reinterpret_cast<const float4*>(&W[(size_t)(nW0 + row) * 512 + kk0 + c4 * 4]);
            Bst[c4*4+0][row] = w.x; Bst[c4*4+1][row] = w.y;
            Bst[c4*4+2][row] = w.z; Bst[c4*4+3][row] = w.w;
        }
        __syncthreads();
#pragma unroll
        for (int kk = 0; kk < 32; kk++) {
            float a[8], bb[8];
            *reinterpret_cast<float4*>(&a[0])  = *reinterpret_cast<const float4*>(&Ast[kk][ty*8]);
            *reinterpret_cast<float4*>(&a[4])  = *reinterpret_cast<const float4*>(&Ast[kk][ty*8+4]);
            *reinterpret_cast<float4*>(&bb[0]) = *reinterpret_cast<const float4*>(&Bst[kk][tx*8]);
            *reinterpret_cast<float4*>(&bb[4]) = *reinterpret_cast<const float4*>(&Bst[kk][tx*8+4]);
#pragma unroll
            for (int i = 0; i < 8; i++)
#pragma unroll
                for (int j = 0; j < 8; j++) acc[i][j] += a[i] * bb[j];
        }
        __syncthreads();
    }

    // epilogue: n-cols of one thread are 8 contiguous d's inside one head
    const int nh = (n0 + tx*8) & 1023;
    const int kh = nh >> 8, d0 = nh & 255;
    float bias[8];
#pragma unroll
    for (int j = 0; j < 8; j++) bias[j] = isK ? biasW[(d0 + j) * NH_ + kh] : 0.f;

#pragma unroll
    for (int i = 0; i < 8; i++) {
        int m = m0 + ty*8 + i;
        int b = m >> 11, l = m & 2047;
        size_t off = ((size_t)(b * NH_ + kh) * L_ + l) * KE_ + d0;
        float4 v0 = make_float4(acc[i][0]+bias[0], acc[i][1]+bias[1], acc[i][2]+bias[2], acc[i][3]+bias[3]);
        float4 v1 = make_float4(acc[i][4]+bias[4], acc[i][5]+bias[5], acc[i][6]+bias[6], acc[i][7]+bias[7]);
        float* dst = isK ? xkb : xq;
        *reinterpret_cast<float4*>(&dst[off])     = v0;
        *reinterpret_cast<float4*>(&dst[off + 4]) = v1;
    }
}

// ---------------- K2: kn row sums ----------------
__global__ __launch_bounds__(256) void kn_kernel(const float* __restrict__ xkb, float* __restrict__ kn)
{
    int w = threadIdx.x >> 6, l = threadIdx.x & 63;
    int row = blockIdx.x * 4 + w;   // 0..16383
    float4 v = reinterpret_cast<const float4*>(&xkb[(size_t)row * KE_])[l];
    float s = v.x*v.x + v.y*v.y + v.z*v.z + v.w*v.w;
#pragma unroll
    for (int m = 32; m; m >>= 1) s += __shfl_xor(s, m, 64);
    if (l == 0) kn[row] = s;
}

// ---------------- K3: fused flash attention ----------------
// grid (64, 8): blockIdx.x -> 32 query rows; blockIdx.y -> (b,k)
// 256 thr: wave w = i-group (8 rows); lane: kp=l>>3 (k-part), jg=l&7 (j-group)
__global__ __launch_bounds__(256) void attn_kernel(
    const float* __restrict__ xq, const float* __restrict__ xkb,
    const float* __restrict__ kn, const float* __restrict__ xsa,
    float* __restrict__ ybar)
{
    __shared__ float Qs[256][36];    // k-major Q tile     36.9 KB
    __shared__ float Ks[128][68];    // k-major K chunk    34.8 KB
    __shared__ float Vs[16][516];    // V chunk            33.0 KB
    __shared__ float Ps[64][36];     // P[j][i]             9.2 KB
    __shared__ float kns[64];

    const int t = threadIdx.x;
    const int w = t >> 6;          // wave = i-group
    const int lane = t & 63;
    const int kp = lane >> 3;
    const int jg = lane & 7;
    const int bk = blockIdx.y;
    const int b  = bk >> 2;
    const int i0 = blockIdx.x * 32;
    const size_t qbase = (size_t)bk * L_ * KE_;
    const size_t vbase = (size_t)b  * L_ * E_;

    // load Q tile k-major (32 x 256)
#pragma unroll
    for (int r = 0; r < 8; r++) {
        int idx = t + r * 256;      // 0..2047
        int row = idx >> 6;         // 0..31
        int c4  = idx & 63;         // 0..63
        float4 v = *reinterpret_cast<const float4*>(&xq[qbase + (size_t)(i0 + row) * KE_ + c4 * 4]);
        Qs[c4*4+0][row] = v.x; Qs[c4*4+1][row] = v.y;
        Qs[c4*4+2][row] = v.z; Qs[c4*4+3][row] = v.w;
    }

    float O[8][8];
#pragma unroll
    for (int i = 0; i < 8; i++)
#pragma unroll
        for (int e = 0; e < 8; e++) O[i][e] = 0.f;
    float mrun[8], lrun[8];
#pragma unroll
    for (int i = 0; i < 8; i++) { mrun[i] = -3.0e38f; lrun[i] = 0.f; }

    for (int j0 = 0; j0 < L_; j0 += 64) {
        if (t < 16)
            *reinterpret_cast<float4*>(&kns[t*4]) =
                *reinterpret_cast<const float4*>(&kn[(size_t)bk * L_ + j0 + t*4]);

        float s[8][8];
#pragma unroll
        for (int i = 0; i < 8; i++)
#pragma unroll
            for (int j = 0; j < 8; j++) s[i][j] = 0.f;

        // S = Q.Kb^T over 2 k-chunks of 128
        for (int kc = 0; kc < 2; kc++) {
            __syncthreads();
#pragma unroll
            for (int r = 0; r < 8; r++) {
                int idx = t + r * 256;
                int row = idx >> 5;      // j 0..63
                int c4  = idx & 31;      // k4 0..31
                float4 v = *reinterpret_cast<const float4*>(
                    &xkb[qbase + (size_t)(j0 + row) * KE_ + kc*128 + c4*4]);
                Ks[c4*4+0][row] = v.x; Ks[c4*4+1][row] = v.y;
                Ks[c4*4+2][row] = v.z; Ks[c4*4+3][row] = v.w;
            }
            __syncthreads();
#pragma unroll
            for (int step = 0; step < 16; step++) {
                int klocal = kp + step * 8;
                int kglob  = kc * 128 + klocal;
                float a[8], bb[8];
                *reinterpret_cast<float4*>(&a[0])  = *reinterpret_cast<const float4*>(&Qs[kglob][w*8]);
                *reinterpret_cast<float4*>(&a[4])  = *reinterpret_cast<const float4*>(&Qs[kglob][w*8+4]);
                *reinterpret_cast<float4*>(&bb[0]) = *reinterpret_cast<const float4*>(&Ks[klocal][jg*8]);
                *reinterpret_cast<float4*>(&bb[4]) = *reinterpret_cast<const float4*>(&Ks[klocal][jg*8+4]);
#pragma unroll
                for (int i = 0; i < 8; i++)
#pragma unroll
                    for (int j = 0; j < 8; j++) s[i][j] += a[i] * bb[j];
            }
        }

        // combine k-parts (lanes xor 8,16,32)
#pragma unroll
        for (int i = 0; i < 8; i++)
#pragma unroll
            for (int j = 0; j < 8; j++) {
                float v = s[i][j];
                v += __shfl_xor(v, 8, 64);
                v += __shfl_xor(v, 16, 64);
                v += __shfl_xor(v, 32, 64);
                s[i][j] = v;
            }

        // scores + online softmax (all lanes redundantly -> everyone has scales)
        float knsl[8];
#pragma unroll
        for (int j = 0; j < 8; j++) knsl[j] = kns[jg*8 + j];

        float mt[8];
#pragma unroll
        for (int i = 0; i < 8; i++) {
            float mx = -3.0e38f;
#pragma unroll
            for (int j = 0; j < 8; j++) {
                float h = s[i][j] * 0.125f - knsl[j] * 0.0625f;   // (2c - kn)/16
                s[i][j] = h;
                mx = fmaxf(mx, h);
            }
            mx = fmaxf(mx, __shfl_xor(mx, 1, 64));
            mx = fmaxf(mx, __shfl_xor(mx, 2, 64));
            mx = fmaxf(mx, __shfl_xor(mx, 4, 64));
            mt[i] = mx;
        }
        float oscale[8];
#pragma unroll
        for (int i = 0; i < 8; i++) {
            float mnew = fmaxf(mrun[i], mt[i]);
            oscale[i] = __expf(mrun[i] - mnew);
            float ls = 0.f;
#pragma unroll
            for (int j = 0; j < 8; j++) {
                float e = __expf(s[i][j] - mnew);
                s[i][j] = e;                         // s now holds P
                ls += e;
            }
            ls += __shfl_xor(ls, 1, 64);
            ls += __shfl_xor(ls, 2, 64);
            ls += __shfl_xor(ls, 4, 64);
            lrun[i] = lrun[i] * oscale[i] + ls;
            mrun[i] = mnew;
        }

        // write P[j][i] (kp==0 lanes carry canonical copy)
        if (kp == 0) {
#pragma unroll
            for (int j = 0; j < 8; j++) {
                float4 v0 = make_float4(s[0][j], s[1][j], s[2][j], s[3][j]);
                float4 v1 = make_float4(s[4][j], s[5][j], s[6][j], s[7][j]);
                *reinterpret_cast<float4*>(&Ps[jg*8+j][w*8])   = v0;
                *reinterpret_cast<float4*>(&Ps[jg*8+j][w*8+4]) = v1;
            }
        }
        // rescale O
#pragma unroll
        for (int i = 0; i < 8; i++)
#pragma unroll
            for (int e = 0; e < 8; e++) O[i][e] *= oscale[i];

        // PV over 4 V-chunks of 16 rows
        for (int vc = 0; vc < 4; vc++) {
            __syncthreads();   // also makes Ps visible before first chunk
#pragma unroll
            for (int r = 0; r < 8; r++) {
                int idx = t + r * 256;
                int row = idx >> 7;      // 0..15
                int c4  = idx & 127;     // 0..127
                *reinterpret_cast<float4*>(&Vs[row][c4*4]) =
                    *reinterpret_cast<const float4*>(
                        &xsa[vbase + (size_t)(j0 + vc*16 + row) * E_ + c4*4]);
            }
            __syncthreads();
#pragma unroll
            for (int jj = 0; jj < 16; jj++) {
                int jt = vc * 16 + jj;
                float pp[8], vv[8];
                *reinterpret_cast<float4*>(&pp[0]) = *reinterpret_cast<const float4*>(&Ps[jt][w*8]);
                *reinterpret_cast<float4*>(&pp[4]) = *reinterpret_cast<const float4*>(&Ps[jt][w*8+4]);
                *reinterpret_cast<float4*>(&vv[0]) = *reinterpret_cast<const float4*>(&Vs[jj][lane*8]);
                *reinterpret_cast<float4*>(&vv[4]) = *reinterpret_cast<const float4*>(&Vs[jj][lane*8+4]);
#pragma unroll
                for (int i = 0; i < 8; i++)
#pragma unroll
                    for (int e = 0; e < 8; e++) O[i][e] += pp[i] * vv[e];
            }
        }
    }

    // normalize + store
#pragma unroll
    for (int i = 0; i < 8; i++) {
        float inv = 1.f / lrun[i];
        int ig = i0 + w*8 + i;
        size_t off = ((size_t)bk * L_ + ig) * E_ + lane * 8;
        float4 v0 = make_float4(O[i][0]*inv, O[i][1]*inv, O[i][2]*inv, O[i][3]*inv);
        float4 v1 = make_float4(O[i][4]*inv, O[i][5]*inv, O[i][6]*inv, O[i][7]*inv);
        *reinterpret_cast<float4*>(&ybar[off])     = v0;
        *reinterpret_cast<float4*>(&ybar[off + 4]) = v1;
    }
}

// ---------------- K4: per-head combine GEMM + bias2 ----------------
// per (b,k): (2048x512) @ Wv3[k] (512x512); Wv3[k][e][f] = Wv[k*E*E + e*E + f]
__global__ __launch_bounds__(256) void combine_kernel(
    const float* __restrict__ ybar, const float* __restrict__ Wv,
    const float* __restrict__ bias2W, float* __restrict__ out)
{
    __shared__ float Ast[32][132];
    __shared__ float Bst[32][132];
    const int t = threadIdx.x;
    const int m0 = blockIdx.x * 128;   // i
    const int n0 = blockIdx.y * 128;   // f
    const int bk = blockIdx.z;
    const int k = bk & 3, b = bk >> 2;
    const size_t abase = (size_t)bk * L_ * E_;
    const size_t wbase = (size_t)k * E_ * E_;
    const int ty = t >> 4, tx = t & 15;

    float acc[8][8];
#pragma unroll
    for (int i = 0; i < 8; i++)
#pragma unroll
        for (int j = 0; j < 8; j++) acc[i][j] = 0.f;

    for (int kk0 = 0; kk0 < 512; kk0 += 32) {
#pragma unroll
        for (int r = 0; r < 4; r++) {
            int idx = t + r * 256;
            int row = idx >> 3;     // 0..127 (i)
            int c4  = idx & 7;
            float4 v = *reinterpret_cast<const float4*>(&ybar[abase + (size_t)(m0 + row) * E_ + kk0 + c4*4]);
            Ast[c4*4+0][row] = v.x; Ast[c4*4+1][row] = v.y;
            Ast[c4*4+2][row] = v.z; Ast[c4*4+3][row] = v.w;
            int er  = idx >> 5;     // 0..31 (e)
            int fc4 = idx & 31;     // 0..31
            *reinterpret_cast<float4*>(&Bst[er][fc4*4]) =
                *reinterpret_cast<const float4*>(&Wv[wbase + (size_t)(kk0 + er) * E_ + n0 + fc4*4]);
        }
        __syncthreads();
#pragma unroll
        for (int kk = 0; kk < 32; kk++) {
            float a[8], bb[8];
            *reinterpret_cast<float4*>(&a[0])  = *reinterpret_cast<const float4*>(&Ast[kk][ty*8]);
            *reinterpret_cast<float4*>(&a[4])  = *reinterpret_cast<const float4*>(&Ast[kk][ty*8+4]);
            *reinterpret_cast<float4*>(&bb[0]) = *reinterpret_cast<const float4*>(&Bst[kk][tx*8]);
            *reinterpret_cast<float4*>(&bb[4]) = *reinterpret_cast<const float4*>(&Bst[kk][tx*8+4]);
#pragma unroll
            for (int i = 0; i < 8; i++)
#pragma unroll
                for (int j = 0; j < 8; j++) acc[i][j] += a[i] * bb[j];
        }
        __syncthreads();
    }

    float bias[8];
#pragma unroll
    for (int j = 0; j < 8; j++) bias[j] = bias2W[(n0 + tx*8 + j) * NH_ + k];

#pragma unroll
    for (int i = 0; i < 8; i++) {
        int iL = m0 + ty*8 + i;
        size_t ob = ((size_t)b * L_ + iL) * (NH_ * E_) + k * E_ + n0 + tx*8;
        float4 v0 = make_float4(acc[i][0]+bias[0], acc[i][1]+bias[1], acc[i][2]+bias[2], acc[i][3]+bias[3]);
        float4 v1 = make_float4(acc[i][4]+bias[4], acc[i][5]+bias[5], acc[i][6]+bias[6], acc[i][7]+bias[7]);
        *reinterpret_cast<float4*>(&out[ob])     = v0;
        *reinterpret_cast<float4*>(&out[ob + 4]) = v1;
    }
}

extern "C" void kernel_launch(void* const* d_in, const int* in_sizes, int n_in,
                              void* d_out, int out_size, void* d_ws, size_t ws_size,
                              hipStream_t stream)
{
    const float* xsa    = (const float*)d_in[0];
    const float* Wq     = (const float*)d_in[1];
    const float* Wk     = (const float*)d_in[2];
    const float* Wv     = (const float*)d_in[3];
    const float* biasW  = (const float*)d_in[4];
    const float* bias2W = (const float*)d_in[5];
    float* out = (float*)d_out;
    float* ws  = (float*)d_ws;

    float* xq   = ws;                 // 4,194,304 floats
    float* xkb  = ws + 4194304;       // 4,194,304
    float* knv  = ws + 8388608;       //    16,384
    float* ybar = ws + 8404992;       // 8,388,608   (total 64.1 MiB)

    proj_kernel<<<dim3(32, 16), 256, 0, stream>>>(xsa, Wq, Wk, biasW, xq, xkb);
    kn_kernel<<<dim3(4096), 256, 0, stream>>>(xkb, knv);
    attn_kernel<<<dim3(64, 8), 256, 0, stream>>>(xq, xkb, knv, xsa, ybar);
    combine_kernel<<<dim3(16, 4, 8), 256, 0, stream>>>(ybar, Wv, bias2W, out);
}

// Round 3
// 660.308 us; speedup vs baseline: 2.4414x; 2.4414x over previous
//
#include <hip/hip_runtime.h>

// Gaussian Attention, MFMA split-bf16 decomposition:
//   K1 proj:   xq=xsa@Wq^T, xkb=xsa@Wk^T+biasW.T -> bf16 hi/lo, layout (bk,l,d)
//   K1b trans: xsaT hi/lo [b][e][l]  (V operand, j-contiguous)
//   K2 kn:     kn[bk][l] = sum_d xkb^2   (from hi+lo reconstruction)
//   K3 attn:   flash, S=(2*QK^T - kn_j)/16 via 3-MFMA split; P@V via 3-MFMA split
//   K4 combine: out = ybar @ Wv3[k] + bias2  (fp32 vector GEMM, ybar bf16)
//
// ws (ushort units): xqhi 4M | xqlo 4M | xkhi 4M | xklo 4M | xThi 2M | xTlo 2M
//                    | ybar 8M | kn 16K floats   => 56.1 MiB total

#define L_ 2048
#define E_ 512
#define KE_ 256
#define NH_ 4

typedef __bf16 bf16x8 __attribute__((ext_vector_type(8)));
typedef float f32x4 __attribute__((ext_vector_type(4)));

__device__ __forceinline__ float bf2f(unsigned short u){
    union { float f; unsigned int i; } v; v.i = ((unsigned int)u) << 16; return v.f;
}
__device__ __forceinline__ unsigned short f2bf(float x){
    union { float f; unsigned int i; } v; v.f = x;
    unsigned int r = v.i + 0x7fffu + ((v.i >> 16) & 1u);
    return (unsigned short)(r >> 16);
}

// ---------------- K1: projection GEMM (M=4096, N=2048, K=512), bf16 hi/lo out ----
__global__ __launch_bounds__(256) void proj_kernel(
    const float* __restrict__ xsa, const float* __restrict__ Wq,
    const float* __restrict__ Wk, const float* __restrict__ biasW,
    unsigned short* __restrict__ xqhi, unsigned short* __restrict__ xqlo,
    unsigned short* __restrict__ xkhi, unsigned short* __restrict__ xklo)
{
    __shared__ float Ast[32][132];
    __shared__ float Bst[32][132];
    const int t = threadIdx.x;
    const int m0 = blockIdx.x * 128;
    const int n0 = blockIdx.y * 128;
    const bool isK = (n0 >= 1024);
    const float* W = isK ? Wk : Wq;
    const int nW0 = isK ? (n0 - 1024) : n0;
    const int ty = t >> 4, tx = t & 15;

    float acc[8][8];
#pragma unroll
    for (int i = 0; i < 8; i++)
#pragma unroll
        for (int j = 0; j < 8; j++) acc[i][j] = 0.f;

    for (int kk0 = 0; kk0 < 512; kk0 += 32) {
#pragma unroll
        for (int r = 0; r < 4; r++) {
            int idx = t + r * 256;
            int row = idx >> 3;
            int c4  = idx & 7;
            float4 v = *reinterpret_cast<const float4*>(&xsa[(size_t)(m0 + row) * 512 + kk0 + c4 * 4]);
            Ast[c4*4+0][row] = v.x; Ast[c4*4+1][row] = v.y;
            Ast[c4*4+2][row] = v.z; Ast[c4*4+3][row] = v.w;
            float4 w = *reinterpret_cast<const float4*>(&W[(size_t)(nW0 + row) * 512 + kk0 + c4 * 4]);
            Bst[c4*4+0][row] = w.x; Bst[c4*4+1][row] = w.y;
            Bst[c4*4+2][row] = w.z; Bst[c4*4+3][row] = w.w;
        }
        __syncthreads();
#pragma unroll
        for (int kk = 0; kk < 32; kk++) {
            float a[8], bb[8];
            *reinterpret_cast<float4*>(&a[0])  = *reinterpret_cast<const float4*>(&Ast[kk][ty*8]);
            *reinterpret_cast<float4*>(&a[4])  = *reinterpret_cast<const float4*>(&Ast[kk][ty*8+4]);
            *reinterpret_cast<float4*>(&bb[0]) = *reinterpret_cast<const float4*>(&Bst[kk][tx*8]);
            *reinterpret_cast<float4*>(&bb[4]) = *reinterpret_cast<const float4*>(&Bst[kk][tx*8+4]);
#pragma unroll
            for (int i = 0; i < 8; i++)
#pragma unroll
                for (int j = 0; j < 8; j++) acc[i][j] += a[i] * bb[j];
        }
        __syncthreads();
    }

    const int nh = (n0 + tx*8) & 1023;
    const int kh = nh >> 8, d0 = nh & 255;
    float bias[8];
#pragma unroll
    for (int j = 0; j < 8; j++) bias[j] = isK ? biasW[(d0 + j) * NH_ + kh] : 0.f;
    unsigned short* dsthi = isK ? xkhi : xqhi;
    unsigned short* dstlo = isK ? xklo : xqlo;

#pragma unroll
    for (int i = 0; i < 8; i++) {
        int m = m0 + ty*8 + i;
        int b = m >> 11, l = m & 2047;
        size_t off = ((size_t)((b * NH_ + kh) * L_ + l)) * KE_ + d0;
        unsigned short th[8], tl[8];
#pragma unroll
        for (int j = 0; j < 8; j++) {
            float x = acc[i][j] + bias[j];
            unsigned short hh = f2bf(x);
            th[j] = hh;
            tl[j] = f2bf(x - bf2f(hh));
        }
        *reinterpret_cast<ushort4*>(&dsthi[off])     = *reinterpret_cast<ushort4*>(&th[0]);
        *reinterpret_cast<ushort4*>(&dsthi[off + 4]) = *reinterpret_cast<ushort4*>(&th[4]);
        *reinterpret_cast<ushort4*>(&dstlo[off])     = *reinterpret_cast<ushort4*>(&tl[0]);
        *reinterpret_cast<ushort4*>(&dstlo[off + 4]) = *reinterpret_cast<ushort4*>(&tl[4]);
    }
}

// ---------------- K1b: transpose xsa -> xsaT hi/lo [b][e][l] ----------------
__global__ __launch_bounds__(256) void trans_kernel(
    const float* __restrict__ xsa, unsigned short* __restrict__ xThi,
    unsigned short* __restrict__ xTlo)
{
    __shared__ float T[64][65];
    const int t = threadIdx.x;
    const int l0 = blockIdx.x * 64, e0 = blockIdx.y * 64, b = blockIdx.z;
#pragma unroll
    for (int p = 0; p < 4; p++) {
        int row = p*16 + (t >> 4);
        int c4 = t & 15;
        float4 v = *reinterpret_cast<const float4*>(&xsa[((size_t)(b*L_ + l0 + row))*E_ + e0 + c4*4]);
        T[row][c4*4+0] = v.x; T[row][c4*4+1] = v.y;
        T[row][c4*4+2] = v.z; T[row][c4*4+3] = v.w;
    }
    __syncthreads();
#pragma unroll
    for (int p = 0; p < 16; p++) {
        int e = p*4 + (t >> 6);
        int lp = t & 63;
        float x = T[lp][e];
        unsigned short hh = f2bf(x);
        size_t off = ((size_t)(b*E_ + e0 + e))*L_ + l0 + lp;
        xThi[off] = hh;
        xTlo[off] = f2bf(x - bf2f(hh));
    }
}

// ---------------- K2: kn row sums from bf16 hi/lo ----------------
__global__ __launch_bounds__(256) void kn_kernel(
    const unsigned short* __restrict__ xkhi, const unsigned short* __restrict__ xklo,
    float* __restrict__ kn)
{
    const int w = threadIdx.x >> 6, lane = threadIdx.x & 63;
    const int row = blockIdx.x * 4 + w;
    ushort4 uh = *reinterpret_cast<const ushort4*>(&xkhi[(size_t)row * KE_ + lane*4]);
    ushort4 ul = *reinterpret_cast<const ushort4*>(&xklo[(size_t)row * KE_ + lane*4]);
    float x0 = bf2f(uh.x) + bf2f(ul.x);
    float x1 = bf2f(uh.y) + bf2f(ul.y);
    float x2 = bf2f(uh.z) + bf2f(ul.z);
    float x3 = bf2f(uh.w) + bf2f(ul.w);
    float s = x0*x0 + x1*x1 + x2*x2 + x3*x3;
#pragma unroll
    for (int m = 32; m; m >>= 1) s += __shfl_xor(s, m, 64);
    if (lane == 0) kn[row] = s;
}

// ---------------- K3: fused flash attention, MFMA split-bf16 ----------------
// grid (32, 8): 64 q-rows per block, bk = blockIdx.y. 512 thr = 8 waves.
// wave w = rg*2 + h: rg = 16-row group; h = j-subtile (QK^T) AND e-half (PV).
__global__ __launch_bounds__(512, 2) void attn_kernel(
    const unsigned short* __restrict__ xqhi, const unsigned short* __restrict__ xqlo,
    const unsigned short* __restrict__ xkhi, const unsigned short* __restrict__ xklo,
    const unsigned short* __restrict__ xThi, const unsigned short* __restrict__ xTlo,
    const float* __restrict__ knp, unsigned short* __restrict__ ybar)
{
    __shared__ __align__(16) unsigned short Khi[32*256], Klo[32*256];   // 16 KB each
    __shared__ __align__(16) unsigned short Vhi[512*32], Vlo[512*32];   // 32 KB each
    __shared__ __align__(16) unsigned short Phi[64*32],  Plo[64*32];    //  4 KB each
    __shared__ float statm[8][16], statl[8][16];
    __shared__ __align__(16) float kns[32];

    const int t = threadIdx.x;
    const int w = t >> 6, lane = t & 63;
    const int rg = w >> 1, h = w & 1;
    const int l15 = lane & 15, l4 = lane >> 4;
    const int xmask = (lane & 7) << 4;
    const int bk = blockIdx.y, b = bk >> 2;
    const int i0 = blockIdx.x * 64;

    char* const kh_b = (char*)Khi; char* const kl_b = (char*)Klo;
    char* const vh_b = (char*)Vhi; char* const vl_b = (char*)Vlo;
    char* const ph_b = (char*)Phi; char* const pl_b = (char*)Plo;

    // Q fragments in registers: A[row=l&15][k=(l>>4)*8+reg] per 32-wide k-step
    bf16x8 qh[8], ql[8];
    {
        const size_t qoff = ((size_t)(bk*L_ + i0 + rg*16 + l15))*KE_ + l4*8;
#pragma unroll
        for (int ks = 0; ks < 8; ks++) {
            qh[ks] = *reinterpret_cast<const bf16x8*>(xqhi + qoff + ks*32);
            ql[ks] = *reinterpret_cast<const bf16x8*>(xqlo + qoff + ks*32);
        }
    }

    f32x4 O[16];
#pragma unroll
    for (int e = 0; e < 16; e++) O[e] = (f32x4){0.f,0.f,0.f,0.f};
    float mrun[4] = {-1e30f,-1e30f,-1e30f,-1e30f};
    float lrun[4] = {0.f,0.f,0.f,0.f};

    for (int j0 = 0; j0 < L_; j0 += 32) {
        __syncthreads();    // prior iter's LDS reads complete
        // ---- stage K tile (32j x 256d, hi/lo), swizzled ----
        {
            const size_t krow0 = (size_t)(bk*L_ + j0);
#pragma unroll
            for (int r = 0; r < 4; r++) {
                int c = t + r*512;
                int arr = c >> 10;
                int cc = c & 1023;
                int j = cc >> 5, dc = cc & 31;
                const unsigned short* src = (arr ? xklo : xkhi) + (krow0 + j)*KE_ + dc*8;
                uint4 v = *reinterpret_cast<const uint4*>(src);
                char* dst = (arr ? kl_b : kh_b) + (((j*512) + dc*16) ^ ((j & 7) << 4));
                *reinterpret_cast<uint4*>(dst) = v;
            }
            // ---- stage V tile transposed (512e x 32j, hi/lo), swizzled ----
#pragma unroll
            for (int r = 0; r < 8; r++) {
                int c = t + r*512;
                int arr = c >> 11;
                int cc = c & 2047;
                int e = cc >> 2, jc = cc & 3;
                const unsigned short* src = (arr ? xTlo : xThi) + ((size_t)(b*E_ + e))*L_ + j0 + jc*8;
                uint4 v = *reinterpret_cast<const uint4*>(src);
                char* dst = (arr ? vl_b : vh_b) + (((e*64) + jc*16) ^ ((e & 7) << 4));
                *reinterpret_cast<uint4*>(dst) = v;
            }
            if (t < 8)
                *reinterpret_cast<f32x4*>(&kns[t*4]) =
                    *reinterpret_cast<const f32x4*>(knp + (size_t)bk*L_ + j0 + t*4);
        }
        __syncthreads();

        // ---- QK^T: S[16 rows][16 j] for subtile h, 3-MFMA split ----
        f32x4 sac = (f32x4){0.f,0.f,0.f,0.f};
        {
            const int kbase = (h*16 + l15)*512 + l4*16;
#pragma unroll
            for (int ks = 0; ks < 8; ks++) {
                bf16x8 bh = *reinterpret_cast<const bf16x8*>(kh_b + ((kbase + ks*64) ^ xmask));
                bf16x8 bl = *reinterpret_cast<const bf16x8*>(kl_b + ((kbase + ks*64) ^ xmask));
                sac = __builtin_amdgcn_mfma_f32_16x16x32_bf16(qh[ks], bh, sac, 0, 0, 0);
                sac = __builtin_amdgcn_mfma_f32_16x16x32_bf16(qh[ks], bl, sac, 0, 0, 0);
                sac = __builtin_amdgcn_mfma_f32_16x16x32_bf16(ql[ks], bh, sac, 0, 0, 0);
            }
        }

        // ---- scores + online softmax (rows distributed: row=(l>>4)*4+reg) ----
        const float knj = kns[h*16 + l15];
        float s[4], mloc[4];
#pragma unroll
        for (int r4 = 0; r4 < 4; r4++) {
            s[r4] = sac[r4]*0.125f - knj*0.0625f;     // (2*cross - kn)/16
            float mx = s[r4];
            mx = fmaxf(mx, __shfl_xor(mx, 1, 64));
            mx = fmaxf(mx, __shfl_xor(mx, 2, 64));
            mx = fmaxf(mx, __shfl_xor(mx, 4, 64));
            mx = fmaxf(mx, __shfl_xor(mx, 8, 64));
            mloc[r4] = mx;
        }
        if (l15 == 0) {
#pragma unroll
            for (int r4 = 0; r4 < 4; r4++) statm[w][l4*4 + r4] = mloc[r4];
        }
        __syncthreads();
        float osc[4], pv_[4], ls[4];
#pragma unroll
        for (int r4 = 0; r4 < 4; r4++) {
            float mo = statm[w ^ 1][l4*4 + r4];
            float mnew = fmaxf(mrun[r4], fmaxf(mloc[r4], mo));
            osc[r4] = __expf(mrun[r4] - mnew);
            mrun[r4] = mnew;
            float p = __expf(s[r4] - mnew);
            pv_[r4] = p;
            float sm = p;
            sm += __shfl_xor(sm, 1, 64);
            sm += __shfl_xor(sm, 2, 64);
            sm += __shfl_xor(sm, 4, 64);
            sm += __shfl_xor(sm, 8, 64);
            ls[r4] = sm;
        }
        if (l15 == 0) {
#pragma unroll
            for (int r4 = 0; r4 < 4; r4++) statl[w][l4*4 + r4] = ls[r4];
        }
        // write P hi/lo to LDS (swizzled), layout [64 rows][32 j]
        {
            const int jcol2 = (h*16 + l15)*2;
#pragma unroll
            for (int r4 = 0; r4 < 4; r4++) {
                int rw = rg*16 + l4*4 + r4;
                int off = ((rw*64) + jcol2) ^ ((rw & 7) << 4);
                unsigned short hh = f2bf(pv_[r4]);
                float rem = pv_[r4] - bf2f(hh);
                *reinterpret_cast<unsigned short*>(ph_b + off) = hh;
                *reinterpret_cast<unsigned short*>(pl_b + off) = f2bf(rem);
            }
        }
        __syncthreads();
#pragma unroll
        for (int r4 = 0; r4 < 4; r4++) {
            float lo_ = statl[w ^ 1][l4*4 + r4];
            lrun[r4] = lrun[r4]*osc[r4] + ls[r4] + lo_;
        }
#pragma unroll
        for (int e = 0; e < 16; e++) {
            O[e][0] *= osc[0]; O[e][1] *= osc[1];
            O[e][2] *= osc[2]; O[e][3] *= osc[3];
        }
        // ---- PV: O[16 rows][e-half 256] += P @ V, 3-MFMA split ----
        {
            const int poff = ((rg*16 + l15)*64 + l4*16) ^ xmask;
            bf16x8 pah = *reinterpret_cast<const bf16x8*>(ph_b + poff);
            bf16x8 pal = *reinterpret_cast<const bf16x8*>(pl_b + poff);
            const int vbase0 = (h*256 + l15)*64 + l4*16;
#pragma unroll
            for (int et = 0; et < 16; et++) {
                int voff = (vbase0 + et*1024) ^ xmask;
                bf16x8 vh = *reinterpret_cast<const bf16x8*>(vh_b + voff);
                bf16x8 vl = *reinterpret_cast<const bf16x8*>(vl_b + voff);
                O[et] = __builtin_amdgcn_mfma_f32_16x16x32_bf16(pah, vh, O[et], 0, 0, 0);
                O[et] = __builtin_amdgcn_mfma_f32_16x16x32_bf16(pal, vh, O[et], 0, 0, 0);
                O[et] = __builtin_amdgcn_mfma_f32_16x16x32_bf16(pah, vl, O[et], 0, 0, 0);
            }
        }
    }

    // ---- normalize + store ybar (bf16) ----
#pragma unroll
    for (int r4 = 0; r4 < 4; r4++) {
        float inv = 1.f / lrun[r4];
        int row = i0 + rg*16 + l4*4 + r4;
        size_t base = ((size_t)(bk*L_ + row))*E_ + h*256 + l15;
#pragma unroll
        for (int et = 0; et < 16; et++)
            ybar[base + et*16] = f2bf(O[et][r4] * inv);
    }
}

// ---------------- K4: per-head combine GEMM + bias2 (ybar bf16 in) ----------
__global__ __launch_bounds__(256) void combine_kernel(
    const unsigned short* __restrict__ ybar, const float* __restrict__ Wv,
    const float* __restrict__ bias2W, float* __restrict__ out)
{
    __shared__ float Ast[32][132];
    __shared__ float Bst[32][132];
    const int t = threadIdx.x;
    const int m0 = blockIdx.x * 128;
    const int n0 = blockIdx.y * 128;
    const int bk = blockIdx.z;
    const int k = bk & 3, b = bk >> 2;
    const size_t abase = (size_t)bk * L_ * E_;
    const size_t wbase = (size_t)k * E_ * E_;
    const int ty = t >> 4, tx = t & 15;

    float acc[8][8];
#pragma unroll
    for (int i = 0; i < 8; i++)
#pragma unroll
        for (int j = 0; j < 8; j++) acc[i][j] = 0.f;

    for (int kk0 = 0; kk0 < 512; kk0 += 32) {
#pragma unroll
        for (int r = 0; r < 4; r++) {
            int idx = t + r * 256;
            int row = idx >> 3;
            int c4  = idx & 7;
            ushort4 u = *reinterpret_cast<const ushort4*>(&ybar[abase + (size_t)(m0 + row) * E_ + kk0 + c4*4]);
            Ast[c4*4+0][row] = bf2f(u.x); Ast[c4*4+1][row] = bf2f(u.y);
            Ast[c4*4+2][row] = bf2f(u.z); Ast[c4*4+3][row] = bf2f(u.w);
            int er  = idx >> 5;
            int fc4 = idx & 31;
            *reinterpret_cast<float4*>(&Bst[er][fc4*4]) =
                *reinterpret_cast<const float4*>(&Wv[wbase + (size_t)(kk0 + er) * E_ + n0 + fc4*4]);
        }
        __syncthreads();
#pragma unroll
        for (int kk = 0; kk < 32; kk++) {
            float a[8], bb[8];
            *reinterpret_cast<float4*>(&a[0])  = *reinterpret_cast<const float4*>(&Ast[kk][ty*8]);
            *reinterpret_cast<float4*>(&a[4])  = *reinterpret_cast<const float4*>(&Ast[kk][ty*8+4]);
            *reinterpret_cast<float4*>(&bb[0]) = *reinterpret_cast<const float4*>(&Bst[kk][tx*8]);
            *reinterpret_cast<float4*>(&bb[4]) = *reinterpret_cast<const float4*>(&Bst[kk][tx*8+4]);
#pragma unroll
            for (int i = 0; i < 8; i++)
#pragma unroll
                for (int j = 0; j < 8; j++) acc[i][j] += a[i] * bb[j];
        }
        __syncthreads();
    }

    float bias[8];
#pragma unroll
    for (int j = 0; j < 8; j++) bias[j] = bias2W[(n0 + tx*8 + j) * NH_ + k];

#pragma unroll
    for (int i = 0; i < 8; i++) {
        int iL = m0 + ty*8 + i;
        size_t ob = ((size_t)b * L_ + iL) * (NH_ * E_) + k * E_ + n0 + tx*8;
        float4 v0 = make_float4(acc[i][0]+bias[0], acc[i][1]+bias[1], acc[i][2]+bias[2], acc[i][3]+bias[3]);
        float4 v1 = make_float4(acc[i][4]+bias[4], acc[i][5]+bias[5], acc[i][6]+bias[6], acc[i][7]+bias[7]);
        *reinterpret_cast<float4*>(&out[ob])     = v0;
        *reinterpret_cast<float4*>(&out[ob + 4]) = v1;
    }
}

extern "C" void kernel_launch(void* const* d_in, const int* in_sizes, int n_in,
                              void* d_out, int out_size, void* d_ws, size_t ws_size,
                              hipStream_t stream)
{
    const float* xsa    = (const float*)d_in[0];
    const float* Wq     = (const float*)d_in[1];
    const float* Wk     = (const float*)d_in[2];
    const float* Wv     = (const float*)d_in[3];
    const float* biasW  = (const float*)d_in[4];
    const float* bias2W = (const float*)d_in[5];
    float* out = (float*)d_out;

    unsigned short* ws16 = (unsigned short*)d_ws;
    unsigned short* xqhi = ws16;                       // 4,194,304
    unsigned short* xqlo = ws16 + 4194304;
    unsigned short* xkhi = ws16 + 8388608;
    unsigned short* xklo = ws16 + 12582912;
    unsigned short* xThi = ws16 + 16777216;            // 2,097,152
    unsigned short* xTlo = ws16 + 18874368;
    unsigned short* ybar = ws16 + 20971520;            // 8,388,608
    float* knv = (float*)(ws16 + 29360128);            // 16,384 floats

    proj_kernel<<<dim3(32, 16), 256, 0, stream>>>(xsa, Wq, Wk, biasW, xqhi, xqlo, xkhi, xklo);
    trans_kernel<<<dim3(32, 8, 2), 256, 0, stream>>>(xsa, xThi, xTlo);
    kn_kernel<<<dim3(4096), 256, 0, stream>>>(xkhi, xklo, knv);
    attn_kernel<<<dim3(32, 8), 512, 0, stream>>>(xqhi, xqlo, xkhi, xklo, xThi, xTlo, knv, ybar);
    combine_kernel<<<dim3(16, 4, 8), 256, 0, stream>>>(ybar, Wv, bias2W, out);
}

// Round 7
// 525.088 us; speedup vs baseline: 3.0702x; 1.2575x over previous
//
#include <hip/hip_runtime.h>

// Gaussian Attention, MFMA split-bf16, swapped-QK^T / P-in-registers attention:
//   K1 proj:   xq=xsa@Wq^T, xkb=xsa@Wk^T+biasW.T -> bf16 hi/lo, layout (bk,l,d)
//   K1b trans: xsaT hi/lo [b][e][l]  (V staging source, j-contiguous)
//   K2 kn:     kn[bk][l] = sum_d xkb^2
//   K3 attn:   flash; S=(2*K.Q^T - kn_j)/16 via 3-MFMA split (swapped: lane l15 = q-row,
//              softmax lane-local, P stays in regs as PV A-frag via pi-ordered V slots);
//              K via global_load_lds double-buffered; V reg-staged 1 tile ahead; 2 barriers/iter.
//   K4 combine: out = ybar @ Wv3[k] + bias2  (fp32 vector GEMM, ybar bf16)

#define L_ 2048
#define E_ 512
#define KE_ 256
#define NH_ 4

typedef __bf16 bf16x8 __attribute__((ext_vector_type(8)));
typedef float f32x4 __attribute__((ext_vector_type(4)));

__device__ __forceinline__ float bf2f(unsigned short u){
    union { float f; unsigned int i; } v; v.i = ((unsigned int)u) << 16; return v.f;
}
__device__ __forceinline__ unsigned short f2bf(float x){
    union { float f; unsigned int i; } v; v.f = x;
    unsigned int r = v.i + 0x7fffu + ((v.i >> 16) & 1u);
    return (unsigned short)(r >> 16);
}
__device__ __forceinline__ void gll16(const void* g, void* l){
    __builtin_amdgcn_global_load_lds((const __attribute__((address_space(1))) void*)g,
                                     (__attribute__((address_space(3))) void*)l, 16, 0, 0);
}

// ---------------- K1: projection GEMM (M=4096, N=2048, K=512), bf16 hi/lo out ----
__global__ __launch_bounds__(256) void proj_kernel(
    const float* __restrict__ xsa, const float* __restrict__ Wq,
    const float* __restrict__ Wk, const float* __restrict__ biasW,
    unsigned short* __restrict__ xqhi, unsigned short* __restrict__ xqlo,
    unsigned short* __restrict__ xkhi, unsigned short* __restrict__ xklo)
{
    __shared__ float Ast[32][132];
    __shared__ float Bst[32][132];
    const int t = threadIdx.x;
    const int m0 = blockIdx.x * 128;
    const int n0 = blockIdx.y * 128;
    const bool isK = (n0 >= 1024);
    const float* W = isK ? Wk : Wq;
    const int nW0 = isK ? (n0 - 1024) : n0;
    const int ty = t >> 4, tx = t & 15;

    float acc[8][8];
#pragma unroll
    for (int i = 0; i < 8; i++)
#pragma unroll
        for (int j = 0; j < 8; j++) acc[i][j] = 0.f;

    for (int kk0 = 0; kk0 < 512; kk0 += 32) {
#pragma unroll
        for (int r = 0; r < 4; r++) {
            int idx = t + r * 256;
            int row = idx >> 3;
            int c4  = idx & 7;
            float4 v = *reinterpret_cast<const float4*>(&xsa[(size_t)(m0 + row) * 512 + kk0 + c4 * 4]);
            Ast[c4*4+0][row] = v.x; Ast[c4*4+1][row] = v.y;
            Ast[c4*4+2][row] = v.z; Ast[c4*4+3][row] = v.w;
            float4 w = *reinterpret_cast<const float4*>(&W[(size_t)(nW0 + row) * 512 + kk0 + c4 * 4]);
            Bst[c4*4+0][row] = w.x; Bst[c4*4+1][row] = w.y;
            Bst[c4*4+2][row] = w.z; Bst[c4*4+3][row] = w.w;
        }
        __syncthreads();
#pragma unroll
        for (int kk = 0; kk < 32; kk++) {
            float a[8], bb[8];
            *reinterpret_cast<float4*>(&a[0])  = *reinterpret_cast<const float4*>(&Ast[kk][ty*8]);
            *reinterpret_cast<float4*>(&a[4])  = *reinterpret_cast<const float4*>(&Ast[kk][ty*8+4]);
            *reinterpret_cast<float4*>(&bb[0]) = *reinterpret_cast<const float4*>(&Bst[kk][tx*8]);
            *reinterpret_cast<float4*>(&bb[4]) = *reinterpret_cast<const float4*>(&Bst[kk][tx*8+4]);
#pragma unroll
            for (int i = 0; i < 8; i++)
#pragma unroll
                for (int j = 0; j < 8; j++) acc[i][j] += a[i] * bb[j];
        }
        __syncthreads();
    }

    const int nh = (n0 + tx*8) & 1023;
    const int kh = nh >> 8, d0 = nh & 255;
    float bias[8];
#pragma unroll
    for (int j = 0; j < 8; j++) bias[j] = isK ? biasW[(d0 + j) * NH_ + kh] : 0.f;
    unsigned short* dsthi = isK ? xkhi : xqhi;
    unsigned short* dstlo = isK ? xklo : xqlo;

#pragma unroll
    for (int i = 0; i < 8; i++) {
        int m = m0 + ty*8 + i;
        int b = m >> 11, l = m & 2047;
        size_t off = ((size_t)((b * NH_ + kh) * L_ + l)) * KE_ + d0;
        unsigned short th[8], tl[8];
#pragma unroll
        for (int j = 0; j < 8; j++) {
            float x = acc[i][j] + bias[j];
            unsigned short hh = f2bf(x);
            th[j] = hh;
            tl[j] = f2bf(x - bf2f(hh));
        }
        *reinterpret_cast<ushort4*>(&dsthi[off])     = *reinterpret_cast<ushort4*>(&th[0]);
        *reinterpret_cast<ushort4*>(&dsthi[off + 4]) = *reinterpret_cast<ushort4*>(&th[4]);
        *reinterpret_cast<ushort4*>(&dstlo[off])     = *reinterpret_cast<ushort4*>(&tl[0]);
        *reinterpret_cast<ushort4*>(&dstlo[off + 4]) = *reinterpret_cast<ushort4*>(&tl[4]);
    }
}

// ---------------- K1b: transpose xsa -> xsaT hi/lo [b][e][l] ----------------
__global__ __launch_bounds__(256) void trans_kernel(
    const float* __restrict__ xsa, unsigned short* __restrict__ xThi,
    unsigned short* __restrict__ xTlo)
{
    __shared__ float T[64][65];
    const int t = threadIdx.x;
    const int l0 = blockIdx.x * 64, e0 = blockIdx.y * 64, b = blockIdx.z;
#pragma unroll
    for (int p = 0; p < 4; p++) {
        int row = p*16 + (t >> 4);
        int c4 = t & 15;
        float4 v = *reinterpret_cast<const float4*>(&xsa[((size_t)(b*L_ + l0 + row))*E_ + e0 + c4*4]);
        T[row][c4*4+0] = v.x; T[row][c4*4+1] = v.y;
        T[row][c4*4+2] = v.z; T[row][c4*4+3] = v.w;
    }
    __syncthreads();
#pragma unroll
    for (int p = 0; p < 16; p++) {
        int e = p*4 + (t >> 6);
        int lp = t & 63;
        float x = T[lp][e];
        unsigned short hh = f2bf(x);
        size_t off = ((size_t)(b*E_ + e0 + e))*L_ + l0 + lp;
        xThi[off] = hh;
        xTlo[off] = f2bf(x - bf2f(hh));
    }
}

// ---------------- K2: kn row sums from bf16 hi/lo ----------------
__global__ __launch_bounds__(256) void kn_kernel(
    const unsigned short* __restrict__ xkhi, const unsigned short* __restrict__ xklo,
    float* __restrict__ kn)
{
    const int w = threadIdx.x >> 6, lane = threadIdx.x & 63;
    const int row = blockIdx.x * 4 + w;
    ushort4 uh = *reinterpret_cast<const ushort4*>(&xkhi[(size_t)row * KE_ + lane*4]);
    ushort4 ul = *reinterpret_cast<const ushort4*>(&xklo[(size_t)row * KE_ + lane*4]);
    float x0 = bf2f(uh.x) + bf2f(ul.x);
    float x1 = bf2f(uh.y) + bf2f(ul.y);
    float x2 = bf2f(uh.z) + bf2f(ul.z);
    float x3 = bf2f(uh.w) + bf2f(ul.w);
    float s = x0*x0 + x1*x1 + x2*x2 + x3*x3;
#pragma unroll
    for (int m = 32; m; m >>= 1) s += __shfl_xor(s, m, 64);
    if (lane == 0) kn[row] = s;
}

// ---------------- K3: fused flash attention, swapped-QKT, P-in-regs ----------
// grid (32, 8), 256 thr = 4 waves. Wave w owns q-rows i0+w*16..+15 (lane l15 = row),
// all 32 j of the tile, all 512 e. KVBLK=32, K double-buffered via global_load_lds,
// V reg-staged one tile ahead into [e][pi-slot] hi/lo. 2 barriers/iter.
__global__ __launch_bounds__(256, 1) void attn_kernel(
    const unsigned short* __restrict__ xqhi, const unsigned short* __restrict__ xqlo,
    const unsigned short* __restrict__ xkhi, const unsigned short* __restrict__ xklo,
    const unsigned short* __restrict__ xThi, const unsigned short* __restrict__ xTlo,
    const float* __restrict__ knp, unsigned short* __restrict__ ybar)
{
    __shared__ __align__(16) char smem[131072];
    char* const kh_b = smem;              // 2 x 16KB K-hi (double buffer)
    char* const kl_b = smem + 32768;      // 2 x 16KB K-lo
    char* const vh_b = smem + 65536;      // 32KB V-hi [e 512][slot 8 x 4bf16]
    char* const vl_b = smem + 98304;      // 32KB V-lo

    const int tid = threadIdx.x;
    const int w = tid >> 6, lane = tid & 63;
    const int l15 = lane & 15, l4 = lane >> 4;
    const int bk = blockIdx.y, b = bk >> 2;
    const int i0 = blockIdx.x * 64;
    const size_t bkL = (size_t)bk * L_;

    // ---- Q B-fragments, held in regs (col = l15 = q-row, k = l4*8+reg) ----
    bf16x8 qh[8], ql[8];
    {
        const size_t qoff = (bkL + i0 + w*16 + l15) * KE_ + l4*8;
#pragma unroll
        for (int ks = 0; ks < 8; ks++) {
            qh[ks] = *reinterpret_cast<const bf16x8*>(xqhi + qoff + ks*32);
            ql[ks] = *reinterpret_cast<const bf16x8*>(xqlo + qoff + ks*32);
        }
    }

    // pi-slot tables: slot s holds j-group pi_g[s] = [0,4,1,5,2,6,3,7]
    // inverse (j-group g -> slot): [0,2,4,6,1,3,5,7]
    const int s0tbl[4] = {0,4,1,5};   // slot of j-group 2*jg2
    const int s1tbl[4] = {2,6,3,7};   // slot of j-group 2*jg2+1
    const int jg2 = tid & 3;
    const int vs0 = s0tbl[jg2]*8, vs1 = s1tbl[jg2]*8;

    uint4 vreg[16];
    // ---- prologue: V(0) loads + K(0) staging ----
#pragma unroll
    for (int r = 0; r < 16; r++) {
        int arr = r >> 3;
        int e = (r & 7)*64 + (tid >> 2);
        const unsigned short* src = (arr ? xTlo : xThi) + ((size_t)(b*E_ + e))*L_ + 0 + jg2*8;
        vreg[r] = *reinterpret_cast<const uint4*>(src);
    }
#pragma unroll
    for (int r = 0; r < 8; r++) {
        int seg = w*8 + r;
        int arr = seg >> 4;
        int sj  = (seg & 15)*2 + (lane >> 5);
        int c   = lane & 31;
        int cp  = c ^ (sj & 7);
        const unsigned short* src = (arr ? xklo : xkhi) + (bkL + 0 + sj)*KE_ + cp*8;
        char* dst = (arr ? kl_b : kh_b) + (seg & 15)*1024;
        gll16(src, dst);
    }
    __syncthreads();

    f32x4 O[32];
#pragma unroll
    for (int e = 0; e < 32; e++) O[e] = (f32x4){0.f,0.f,0.f,0.f};
    float mrun = -1e30f, lrun = 0.f;
    int cur = 0;
    const int axor = (l15 & 7) << 4;

    for (int t = 0; t < 64; ++t) {
        const int j0 = t*32;
        const int jn = (j0 + 32) & (L_-1);

        // ---- 1. write V(t) regs -> LDS [e][pi-slot], swizzled ----
#pragma unroll
        for (int r = 0; r < 16; r++) {
            int e = (r & 7)*64 + (tid >> 2);
            int key = ((e >> 1) & 7) << 4;
            char* base = (r >> 3) ? vl_b : vh_b;
            uint2 lo; lo.x = vreg[r].x; lo.y = vreg[r].y;
            uint2 hi; hi.x = vreg[r].z; hi.y = vreg[r].w;
            *reinterpret_cast<uint2*>(base + ((e*64 + vs0) ^ key)) = lo;
            *reinterpret_cast<uint2*>(base + ((e*64 + vs1) ^ key)) = hi;
        }
        // ---- 2. issue K(t+1) -> other buffer (global_load_lds, pre-swizzled src) ----
#pragma unroll
        for (int r = 0; r < 8; r++) {
            int seg = w*8 + r;
            int arr = seg >> 4;
            int sj  = (seg & 15)*2 + (lane >> 5);
            int c   = lane & 31;
            int cp  = c ^ (sj & 7);
            const unsigned short* src = (arr ? xklo : xkhi) + (bkL + jn + sj)*KE_ + cp*8;
            char* dst = (arr ? kl_b : kh_b) + (cur ^ 1)*16384 + (seg & 15)*1024;
            gll16(src, dst);
        }
        // ---- 3. kn for this tile ----
        float4 kn0 = *reinterpret_cast<const float4*>(knp + bkL + j0 + l4*4);
        float4 kn1 = *reinterpret_cast<const float4*>(knp + bkL + j0 + 16 + l4*4);

        // ---- 4. QK^T (swapped: A=K, B=Q), 3-MFMA split, 2 j-tiles ----
        f32x4 s0 = (f32x4){0.f,0.f,0.f,0.f};
        f32x4 s1 = (f32x4){0.f,0.f,0.f,0.f};
        {
            const char* kh = kh_b + cur*16384;
            const char* kl = kl_b + cur*16384;
            const int arow0 = l15*512, arow1 = (16 + l15)*512;
#pragma unroll
            for (int ks = 0; ks < 8; ks++) {
                int ko = ks*64 + l4*16;
                int a0 = (arow0 + ko) ^ axor;
                int a1 = (arow1 + ko) ^ axor;
                bf16x8 ah0 = *reinterpret_cast<const bf16x8*>(kh + a0);
                bf16x8 al0 = *reinterpret_cast<const bf16x8*>(kl + a0);
                bf16x8 ah1 = *reinterpret_cast<const bf16x8*>(kh + a1);
                bf16x8 al1 = *reinterpret_cast<const bf16x8*>(kl + a1);
                s0 = __builtin_amdgcn_mfma_f32_16x16x32_bf16(ah0, qh[ks], s0, 0, 0, 0);
                s0 = __builtin_amdgcn_mfma_f32_16x16x32_bf16(al0, qh[ks], s0, 0, 0, 0);
                s0 = __builtin_amdgcn_mfma_f32_16x16x32_bf16(ah0, ql[ks], s0, 0, 0, 0);
                s1 = __builtin_amdgcn_mfma_f32_16x16x32_bf16(ah1, qh[ks], s1, 0, 0, 0);
                s1 = __builtin_amdgcn_mfma_f32_16x16x32_bf16(al1, qh[ks], s1, 0, 0, 0);
                s1 = __builtin_amdgcn_mfma_f32_16x16x32_bf16(ah1, ql[ks], s1, 0, 0, 0);
            }
        }

        // ---- 5. lane-local softmax over 32 j (defer-max THR=8) ----
        float h[8];
#pragma unroll
        for (int r = 0; r < 4; r++) {
            h[r]   = s0[r]*0.125f - ((const float*)&kn0)[r]*0.0625f;
            h[4+r] = s1[r]*0.125f - ((const float*)&kn1)[r]*0.0625f;
        }
        float pmax = h[0];
#pragma unroll
        for (int r = 1; r < 8; r++) pmax = fmaxf(pmax, h[r]);
        pmax = fmaxf(pmax, __shfl_xor(pmax, 16, 64));
        pmax = fmaxf(pmax, __shfl_xor(pmax, 32, 64));
        if (__any(pmax > mrun + 8.0f)) {
            float mnew = fmaxf(mrun, pmax);
            float osc = __expf(mrun - mnew);
            mrun = mnew;
            lrun *= osc;
            float osc_pv[4];
#pragma unroll
            for (int r = 0; r < 4; r++) osc_pv[r] = __shfl(osc, l4*4 + r, 64);
#pragma unroll
            for (int et = 0; et < 32; et++) {
                O[et][0] *= osc_pv[0]; O[et][1] *= osc_pv[1];
                O[et][2] *= osc_pv[2]; O[et][3] *= osc_pv[3];
            }
        }
        float p[8], ls = 0.f;
#pragma unroll
        for (int r = 0; r < 8; r++) { p[r] = __expf(h[r] - mrun); ls += p[r]; }
        ls += __shfl_xor(ls, 16, 64);
        ls += __shfl_xor(ls, 32, 64);
        lrun += ls;
        // pack P hi/lo into PV A-fragments (reg order == pi-slot order)
        bf16x8 pah, pal;
        {
            union { unsigned int u[4]; bf16x8 v; } ch, cl;
#pragma unroll
            for (int i = 0; i < 4; i++) {
                unsigned short h0 = f2bf(p[2*i]),   h1 = f2bf(p[2*i+1]);
                unsigned short l0 = f2bf(p[2*i]   - bf2f(h0));
                unsigned short l1 = f2bf(p[2*i+1] - bf2f(h1));
                ch.u[i] = (unsigned int)h0 | ((unsigned int)h1 << 16);
                cl.u[i] = (unsigned int)l0 | ((unsigned int)l1 << 16);
            }
            pah = ch.v; pal = cl.v;
        }

        __syncthreads();   // B1: V(t) visible; K(t+1) drained (early, harmless)

        // ---- 7. issue V(t+1) loads (latency hidden under PV) ----
#pragma unroll
        for (int r = 0; r < 16; r++) {
            int arr = r >> 3;
            int e = (r & 7)*64 + (tid >> 2);
            const unsigned short* src = (arr ? xTlo : xThi) + ((size_t)(b*E_ + e))*L_ + jn + jg2*8;
            vreg[r] = *reinterpret_cast<const uint4*>(src);
        }
        // ---- 8. PV: O[16i][512e] += P @ V, 3-MFMA split ----
#pragma unroll
        for (int et = 0; et < 32; et++) {
            int vo = (et*16 + l15)*64 + l4*16;
            vo ^= ((vo >> 7) & 7) << 4;
            bf16x8 vh = *reinterpret_cast<const bf16x8*>(vh_b + vo);
            bf16x8 vl = *reinterpret_cast<const bf16x8*>(vl_b + vo);
            O[et] = __builtin_amdgcn_mfma_f32_16x16x32_bf16(pah, vh, O[et], 0, 0, 0);
            O[et] = __builtin_amdgcn_mfma_f32_16x16x32_bf16(pal, vh, O[et], 0, 0, 0);
            O[et] = __builtin_amdgcn_mfma_f32_16x16x32_bf16(pah, vl, O[et], 0, 0, 0);
        }

        __syncthreads();   // B2: PV done (V writable next iter); V(t+1)/K(t+1) loads drained
        cur ^= 1;
    }

    // ---- epilogue: normalize + store ybar bf16 ----
    float inv = 1.f / lrun;
    float inv_pv[4];
#pragma unroll
    for (int r = 0; r < 4; r++) inv_pv[r] = __shfl(inv, l4*4 + r, 64);
#pragma unroll
    for (int r = 0; r < 4; r++) {
        int row = i0 + w*16 + l4*4 + r;
        size_t base = (bkL + row)*E_ + l15;
#pragma unroll
        for (int et = 0; et < 32; et++)
            ybar[base + et*16] = f2bf(O[et][r] * inv_pv[r]);
    }
}

// ---------------- K4: per-head combine GEMM + bias2 (ybar bf16 in) ----------
__global__ __launch_bounds__(256) void combine_kernel(
    const unsigned short* __restrict__ ybar, const float* __restrict__ Wv,
    const float* __restrict__ bias2W, float* __restrict__ out)
{
    __shared__ float Ast[32][132];
    __shared__ float Bst[32][132];
    const int t = threadIdx.x;
    const int m0 = blockIdx.x * 128;
    const int n0 = blockIdx.y * 128;
    const int bk = blockIdx.z;
    const int k = bk & 3, b = bk >> 2;
    const size_t abase = (size_t)bk * L_ * E_;
    const size_t wbase = (size_t)k * E_ * E_;
    const int ty = t >> 4, tx = t & 15;

    float acc[8][8];
#pragma unroll
    for (int i = 0; i < 8; i++)
#pragma unroll
        for (int j = 0; j < 8; j++) acc[i][j] = 0.f;

    for (int kk0 = 0; kk0 < 512; kk0 += 32) {
#pragma unroll
        for (int r = 0; r < 4; r++) {
            int idx = t + r * 256;
            int row = idx >> 3;
            int c4  = idx & 7;
            ushort4 u = *reinterpret_cast<const ushort4*>(&ybar[abase + (size_t)(m0 + row) * E_ + kk0 + c4*4]);
            Ast[c4*4+0][row] = bf2f(u.x); Ast[c4*4+1][row] = bf2f(u.y);
            Ast[c4*4+2][row] = bf2f(u.z); Ast[c4*4+3][row] = bf2f(u.w);
            int er  = idx >> 5;
            int fc4 = idx & 31;
            *reinterpret_cast<float4*>(&Bst[er][fc4*4]) =
                *reinterpret_cast<const float4*>(&Wv[wbase + (size_t)(kk0 + er) * E_ + n0 + fc4*4]);
        }
        __syncthreads();
#pragma unroll
        for (int kk = 0; kk < 32; kk++) {
            float a[8], bb[8];
            *reinterpret_cast<float4*>(&a[0])  = *reinterpret_cast<const float4*>(&Ast[kk][ty*8]);
            *reinterpret_cast<float4*>(&a[4])  = *reinterpret_cast<const float4*>(&Ast[kk][ty*8+4]);
            *reinterpret_cast<float4*>(&bb[0]) = *reinterpret_cast<const float4*>(&Bst[kk][tx*8]);
            *reinterpret_cast<float4*>(&bb[4]) = *reinterpret_cast<const float4*>(&Bst[kk][tx*8+4]);
#pragma unroll
            for (int i = 0; i < 8; i++)
#pragma unroll
                for (int j = 0; j < 8; j++) acc[i][j] += a[i] * bb[j];
        }
        __syncthreads();
    }

    float bias[8];
#pragma unroll
    for (int j = 0; j < 8; j++) bias[j] = bias2W[(n0 + tx*8 + j) * NH_ + k];

#pragma unroll
    for (int i = 0; i < 8; i++) {
        int iL = m0 + ty*8 + i;
        size_t ob = ((size_t)b * L_ + iL) * (NH_ * E_) + k * E_ + n0 + tx*8;
        float4 v0 = make_float4(acc[i][0]+bias[0], acc[i][1]+bias[1], acc[i][2]+bias[2], acc[i][3]+bias[3]);
        float4 v1 = make_float4(acc[i][4]+bias[4], acc[i][5]+bias[5], acc[i][6]+bias[6], acc[i][7]+bias[7]);
        *reinterpret_cast<float4*>(&out[ob])     = v0;
        *reinterpret_cast<float4*>(&out[ob + 4]) = v1;
    }
}

extern "C" void kernel_launch(void* const* d_in, const int* in_sizes, int n_in,
                              void* d_out, int out_size, void* d_ws, size_t ws_size,
                              hipStream_t stream)
{
    const float* xsa    = (const float*)d_in[0];
    const float* Wq     = (const float*)d_in[1];
    const float* Wk     = (const float*)d_in[2];
    const float* Wv     = (const float*)d_in[3];
    const float* biasW  = (const float*)d_in[4];
    const float* bias2W = (const float*)d_in[5];
    float* out = (float*)d_out;

    unsigned short* ws16 = (unsigned short*)d_ws;
    unsigned short* xqhi = ws16;                       // 4,194,304
    unsigned short* xqlo = ws16 + 4194304;
    unsigned short* xkhi = ws16 + 8388608;
    unsigned short* xklo = ws16 + 12582912;
    unsigned short* xThi = ws16 + 16777216;            // 2,097,152
    unsigned short* xTlo = ws16 + 18874368;
    unsigned short* ybar = ws16 + 20971520;            // 8,388,608
    float* knv = (float*)(ws16 + 29360128);            // 16,384 floats

    proj_kernel<<<dim3(32, 16), 256, 0, stream>>>(xsa, Wq, Wk, biasW, xqhi, xqlo, xkhi, xklo);
    trans_kernel<<<dim3(32, 8, 2), 256, 0, stream>>>(xsa, xThi, xTlo);
    kn_kernel<<<dim3(4096), 256, 0, stream>>>(xkhi, xklo, knv);
    attn_kernel<<<dim3(32, 8), 256, 0, stream>>>(xqhi, xqlo, xkhi, xklo, xThi, xTlo, knv, ybar);
    combine_kernel<<<dim3(16, 4, 8), 256, 0, stream>>>(ybar, Wv, bias2W, out);
}

// Round 10
// 429.904 us; speedup vs baseline: 3.7499x; 1.2214x over previous
//
#include <hip/hip_runtime.h>

// Gaussian Attention, MFMA split-bf16, swapped-QK^T / P-in-registers attention:
//   K1 proj:   xq=xsa@Wq^T, xkb=xsa@Wk^T+biasW.T -> bf16 hi/lo, layout (bk,l,d)
//   K1b trans: xsaT hi/lo [b][e][l]  (V staging source, j-contiguous)
//   K1c wsplit: Wv -> bf16 hi/lo TRANSPOSED [k][f][e]  (combine B operand)
//   K2 kn:     kn[bk][l] = sum_d xkb^2
//   K3 attn:   flash; 8 waves = 4 row-groups x 2 e-halves (e-split for 2 waves/SIMD TLP;
//              QK^T duplicated per e-half pair). S=(2*K.Q^T - kn_j)/16, 3-MFMA split,
//              softmax lane-local, P in regs; K dbuf global_load_lds; V reg-staged ahead.
//   K4 combine: out = ybar @ (Wvhi+Wvlo) + bias2  (MFMA, 2-MFMA B-split, 128x128 tile)

#define L_ 2048
#define E_ 512
#define KE_ 256
#define NH_ 4

typedef __bf16 bf16x8 __attribute__((ext_vector_type(8)));
typedef float f32x4 __attribute__((ext_vector_type(4)));

__device__ __forceinline__ float bf2f(unsigned short u){
    union { float f; unsigned int i; } v; v.i = ((unsigned int)u) << 16; return v.f;
}
__device__ __forceinline__ unsigned short f2bf(float x){
    union { float f; unsigned int i; } v; v.f = x;
    unsigned int r = v.i + 0x7fffu + ((v.i >> 16) & 1u);
    return (unsigned short)(r >> 16);
}
__device__ __forceinline__ void gll16(const void* g, void* l){
    __builtin_amdgcn_global_load_lds((const __attribute__((address_space(1))) void*)g,
                                     (__attribute__((address_space(3))) void*)l, 16, 0, 0);
}

// ---------------- K1: projection GEMM (M=4096, N=2048, K=512), bf16 hi/lo out ----
__global__ __launch_bounds__(256) void proj_kernel(
    const float* __restrict__ xsa, const float* __restrict__ Wq,
    const float* __restrict__ Wk, const float* __restrict__ biasW,
    unsigned short* __restrict__ xqhi, unsigned short* __restrict__ xqlo,
    unsigned short* __restrict__ xkhi, unsigned short* __restrict__ xklo)
{
    __shared__ float Ast[32][132];
    __shared__ float Bst[32][132];
    const int t = threadIdx.x;
    const int m0 = blockIdx.x * 128;
    const int n0 = blockIdx.y * 128;
    const bool isK = (n0 >= 1024);
    const float* W = isK ? Wk : Wq;
    const int nW0 = isK ? (n0 - 1024) : n0;
    const int ty = t >> 4, tx = t & 15;

    float acc[8][8];
#pragma unroll
    for (int i = 0; i < 8; i++)
#pragma unroll
        for (int j = 0; j < 8; j++) acc[i][j] = 0.f;

    for (int kk0 = 0; kk0 < 512; kk0 += 32) {
#pragma unroll
        for (int r = 0; r < 4; r++) {
            int idx = t + r * 256;
            int row = idx >> 3;
            int c4  = idx & 7;
            float4 v = *reinterpret_cast<const float4*>(&xsa[(size_t)(m0 + row) * 512 + kk0 + c4 * 4]);
            Ast[c4*4+0][row] = v.x; Ast[c4*4+1][row] = v.y;
            Ast[c4*4+2][row] = v.z; Ast[c4*4+3][row] = v.w;
            float4 w = *reinterpret_cast<const float4*>(&W[(size_t)(nW0 + row) * 512 + kk0 + c4 * 4]);
            Bst[c4*4+0][row] = w.x; Bst[c4*4+1][row] = w.y;
            Bst[c4*4+2][row] = w.z; Bst[c4*4+3][row] = w.w;
        }
        __syncthreads();
#pragma unroll
        for (int kk = 0; kk < 32; kk++) {
            float a[8], bb[8];
            *reinterpret_cast<float4*>(&a[0])  = *reinterpret_cast<const float4*>(&Ast[kk][ty*8]);
            *reinterpret_cast<float4*>(&a[4])  = *reinterpret_cast<const float4*>(&Ast[kk][ty*8+4]);
            *reinterpret_cast<float4*>(&bb[0]) = *reinterpret_cast<const float4*>(&Bst[kk][tx*8]);
            *reinterpret_cast<float4*>(&bb[4]) = *reinterpret_cast<const float4*>(&Bst[kk][tx*8+4]);
#pragma unroll
            for (int i = 0; i < 8; i++)
#pragma unroll
                for (int j = 0; j < 8; j++) acc[i][j] += a[i] * bb[j];
        }
        __syncthreads();
    }

    const int nh = (n0 + tx*8) & 1023;
    const int kh = nh >> 8, d0 = nh & 255;
    float bias[8];
#pragma unroll
    for (int j = 0; j < 8; j++) bias[j] = isK ? biasW[(d0 + j) * NH_ + kh] : 0.f;
    unsigned short* dsthi = isK ? xkhi : xqhi;
    unsigned short* dstlo = isK ? xklo : xqlo;

#pragma unroll
    for (int i = 0; i < 8; i++) {
        int m = m0 + ty*8 + i;
        int b = m >> 11, l = m & 2047;
        size_t off = ((size_t)((b * NH_ + kh) * L_ + l)) * KE_ + d0;
        unsigned short th[8], tl[8];
#pragma unroll
        for (int j = 0; j < 8; j++) {
            float x = acc[i][j] + bias[j];
            unsigned short hh = f2bf(x);
            th[j] = hh;
            tl[j] = f2bf(x - bf2f(hh));
        }
        *reinterpret_cast<ushort4*>(&dsthi[off])     = *reinterpret_cast<ushort4*>(&th[0]);
        *reinterpret_cast<ushort4*>(&dsthi[off + 4]) = *reinterpret_cast<ushort4*>(&th[4]);
        *reinterpret_cast<ushort4*>(&dstlo[off])     = *reinterpret_cast<ushort4*>(&tl[0]);
        *reinterpret_cast<ushort4*>(&dstlo[off + 4]) = *reinterpret_cast<ushort4*>(&tl[4]);
    }
}

// ---------------- K1b: transpose xsa -> xsaT hi/lo [b][e][l] ----------------
__global__ __launch_bounds__(256) void trans_kernel(
    const float* __restrict__ xsa, unsigned short* __restrict__ xThi,
    unsigned short* __restrict__ xTlo)
{
    __shared__ float T[64][65];
    const int t = threadIdx.x;
    const int l0 = blockIdx.x * 64, e0 = blockIdx.y * 64, b = blockIdx.z;
#pragma unroll
    for (int p = 0; p < 4; p++) {
        int row = p*16 + (t >> 4);
        int c4 = t & 15;
        float4 v = *reinterpret_cast<const float4*>(&xsa[((size_t)(b*L_ + l0 + row))*E_ + e0 + c4*4]);
        T[row][c4*4+0] = v.x; T[row][c4*4+1] = v.y;
        T[row][c4*4+2] = v.z; T[row][c4*4+3] = v.w;
    }
    __syncthreads();
#pragma unroll
    for (int p = 0; p < 16; p++) {
        int e = p*4 + (t >> 6);
        int lp = t & 63;
        float x = T[lp][e];
        unsigned short hh = f2bf(x);
        size_t off = ((size_t)(b*E_ + e0 + e))*L_ + l0 + lp;
        xThi[off] = hh;
        xTlo[off] = f2bf(x - bf2f(hh));
    }
}

// ---------------- K1c: Wv -> bf16 hi/lo transposed [k][f][e] ----------------
__global__ __launch_bounds__(256) void wsplit_kernel(
    const float* __restrict__ Wv, unsigned short* __restrict__ whiT,
    unsigned short* __restrict__ wloT)
{
    __shared__ float T[64][65];
    const int t = threadIdx.x;
    const int e0 = blockIdx.x * 64, f0 = blockIdx.y * 64, k = blockIdx.z;
#pragma unroll
    for (int p = 0; p < 4; p++) {
        int row = p*16 + (t >> 4);          // e_local
        int c4 = t & 15;
        float4 v = *reinterpret_cast<const float4*>(&Wv[((size_t)(k*E_ + e0 + row))*E_ + f0 + c4*4]);
        T[row][c4*4+0] = v.x; T[row][c4*4+1] = v.y;
        T[row][c4*4+2] = v.z; T[row][c4*4+3] = v.w;
    }
    __syncthreads();
#pragma unroll
    for (int p = 0; p < 16; p++) {
        int fl = p*4 + (t >> 6);            // f_local
        int el = t & 63;                    // e_local
        float x = T[el][fl];
        unsigned short hh = f2bf(x);
        size_t off = ((size_t)(k*E_ + f0 + fl))*E_ + e0 + el;
        whiT[off] = hh;
        wloT[off] = f2bf(x - bf2f(hh));
    }
}

// ---------------- K2: kn row sums from bf16 hi/lo ----------------
__global__ __launch_bounds__(256) void kn_kernel(
    const unsigned short* __restrict__ xkhi, const unsigned short* __restrict__ xklo,
    float* __restrict__ kn)
{
    const int w = threadIdx.x >> 6, lane = threadIdx.x & 63;
    const int row = blockIdx.x * 4 + w;
    ushort4 uh = *reinterpret_cast<const ushort4*>(&xkhi[(size_t)row * KE_ + lane*4]);
    ushort4 ul = *reinterpret_cast<const ushort4*>(&xklo[(size_t)row * KE_ + lane*4]);
    float x0 = bf2f(uh.x) + bf2f(ul.x);
    float x1 = bf2f(uh.y) + bf2f(ul.y);
    float x2 = bf2f(uh.z) + bf2f(ul.z);
    float x3 = bf2f(uh.w) + bf2f(ul.w);
    float s = x0*x0 + x1*x1 + x2*x2 + x3*x3;
#pragma unroll
    for (int m = 32; m; m >>= 1) s += __shfl_xor(s, m, 64);
    if (lane == 0) kn[row] = s;
}

// ---------------- K3: fused flash attention, swapped-QKT, 8-wave e-split ------
// grid (32, 8), 512 thr = 8 waves. Wave w = rg*2 + h: rg = 16-q-row group
// (lane l15 = row), h = e-half (256 e). QK^T duplicated across h (cheap vs TLP).
// KVBLK=32, K double-buffered via global_load_lds, V reg-staged one tile ahead.
__global__ __launch_bounds__(512, 2) void attn_kernel(
    const unsigned short* __restrict__ xqhi, const unsigned short* __restrict__ xqlo,
    const unsigned short* __restrict__ xkhi, const unsigned short* __restrict__ xklo,
    const unsigned short* __restrict__ xThi, const unsigned short* __restrict__ xTlo,
    const float* __restrict__ knp, unsigned short* __restrict__ ybar)
{
    __shared__ __align__(16) char smem[131072];
    char* const kh_b = smem;              // 2 x 16KB K-hi (double buffer)
    char* const kl_b = smem + 32768;      // 2 x 16KB K-lo
    char* const vh_b = smem + 65536;      // 32KB V-hi [e 512][slot 8 x 4bf16]
    char* const vl_b = smem + 98304;      // 32KB V-lo

    const int tid = threadIdx.x;
    const int w = tid >> 6, lane = tid & 63;
    const int rg = w >> 1, h = w & 1;
    const int l15 = lane & 15, l4 = lane >> 4;
    const int bk = blockIdx.y, b = bk >> 2;
    const int i0 = blockIdx.x * 64;
    const size_t bkL = (size_t)bk * L_;

    // ---- Q B-fragments (col = l15 = q-row, k = l4*8+reg); same for both h ----
    bf16x8 qh[8], ql[8];
    {
        const size_t qoff = (bkL + i0 + rg*16 + l15) * KE_ + l4*8;
#pragma unroll
        for (int ks = 0; ks < 8; ks++) {
            qh[ks] = *reinterpret_cast<const bf16x8*>(xqhi + qoff + ks*32);
            ql[ks] = *reinterpret_cast<const bf16x8*>(xqlo + qoff + ks*32);
        }
    }

    // pi-slot tables: slot s holds j-group pi_g[s] = [0,4,1,5,2,6,3,7]
    const int s0tbl[4] = {0,4,1,5};
    const int s1tbl[4] = {2,6,3,7};
    const int jc = tid & 3;
    const int vs0 = s0tbl[jc]*8, vs1 = s1tbl[jc]*8;

    uint4 vreg[8];
    // ---- prologue: V(0) loads + K(0) staging ----
#pragma unroll
    for (int r = 0; r < 8; r++) {
        int arr = r >> 2;
        int e = (r & 3)*128 + (tid >> 2);
        const unsigned short* src = (arr ? xTlo : xThi) + ((size_t)(b*E_ + e))*L_ + 0 + jc*8;
        vreg[r] = *reinterpret_cast<const uint4*>(src);
    }
#pragma unroll
    for (int r = 0; r < 4; r++) {
        int arr = r >> 1;
        int sj  = (r & 1)*16 + w*2 + (lane >> 5);
        int c   = lane & 31;
        int cp  = c ^ (sj & 7);
        const unsigned short* src = (arr ? xklo : xkhi) + (bkL + 0 + sj)*KE_ + cp*8;
        char* dst = (arr ? kl_b : kh_b) + ((r & 1)*512 + w*64)*16;
        gll16(src, dst);
    }
    __syncthreads();

    f32x4 O[16];
#pragma unroll
    for (int e = 0; e < 16; e++) O[e] = (f32x4){0.f,0.f,0.f,0.f};
    float mrun = -1e30f, lrun = 0.f;
    int cur = 0;
    const int axor = (l15 & 7) << 4;

    for (int t = 0; t < 64; ++t) {
        const int j0 = t*32;
        const int jn = (j0 + 32) & (L_-1);

        // ---- 1. write V(t) regs -> LDS [e][pi-slot], swizzled ----
#pragma unroll
        for (int r = 0; r < 8; r++) {
            int e = (r & 3)*128 + (tid >> 2);
            int key = ((e >> 1) & 7) << 4;
            char* base = (r >> 2) ? vl_b : vh_b;
            uint2 lo; lo.x = vreg[r].x; lo.y = vreg[r].y;
            uint2 hi; hi.x = vreg[r].z; hi.y = vreg[r].w;
            *reinterpret_cast<uint2*>(base + ((e*64 + vs0) ^ key)) = lo;
            *reinterpret_cast<uint2*>(base + ((e*64 + vs1) ^ key)) = hi;
        }
        // ---- 2. issue K(t+1) -> other buffer ----
#pragma unroll
        for (int r = 0; r < 4; r++) {
            int arr = r >> 1;
            int sj  = (r & 1)*16 + w*2 + (lane >> 5);
            int c   = lane & 31;
            int cp  = c ^ (sj & 7);
            const unsigned short* src = (arr ? xklo : xkhi) + (bkL + jn + sj)*KE_ + cp*8;
            char* dst = (arr ? kl_b : kh_b) + (cur ^ 1)*16384 + ((r & 1)*512 + w*64)*16;
            gll16(src, dst);
        }
        // ---- 3. kn for this tile ----
        float4 kn0 = *reinterpret_cast<const float4*>(knp + bkL + j0 + l4*4);
        float4 kn1 = *reinterpret_cast<const float4*>(knp + bkL + j0 + 16 + l4*4);

        // ---- 4. QK^T (A=K, B=Q), 3-MFMA split, 2 j-tiles ----
        f32x4 s0 = (f32x4){0.f,0.f,0.f,0.f};
        f32x4 s1 = (f32x4){0.f,0.f,0.f,0.f};
        {
            const char* kh = kh_b + cur*16384;
            const char* kl = kl_b + cur*16384;
            const int arow0 = l15*512, arow1 = (16 + l15)*512;
#pragma unroll
            for (int ks = 0; ks < 8; ks++) {
                int ko = ks*64 + l4*16;
                int a0 = (arow0 + ko) ^ axor;
                int a1 = (arow1 + ko) ^ axor;
                bf16x8 ah0 = *reinterpret_cast<const bf16x8*>(kh + a0);
                bf16x8 al0 = *reinterpret_cast<const bf16x8*>(kl + a0);
                bf16x8 ah1 = *reinterpret_cast<const bf16x8*>(kh + a1);
                bf16x8 al1 = *reinterpret_cast<const bf16x8*>(kl + a1);
                s0 = __builtin_amdgcn_mfma_f32_16x16x32_bf16(ah0, qh[ks], s0, 0, 0, 0);
                s0 = __builtin_amdgcn_mfma_f32_16x16x32_bf16(al0, qh[ks], s0, 0, 0, 0);
                s0 = __builtin_amdgcn_mfma_f32_16x16x32_bf16(ah0, ql[ks], s0, 0, 0, 0);
                s1 = __builtin_amdgcn_mfma_f32_16x16x32_bf16(ah1, qh[ks], s1, 0, 0, 0);
                s1 = __builtin_amdgcn_mfma_f32_16x16x32_bf16(al1, qh[ks], s1, 0, 0, 0);
                s1 = __builtin_amdgcn_mfma_f32_16x16x32_bf16(ah1, ql[ks], s1, 0, 0, 0);
            }
        }

        // ---- 5. lane-local softmax over 32 j (defer-max THR=8) ----
        float hh[8];
#pragma unroll
        for (int r = 0; r < 4; r++) {
            hh[r]   = s0[r]*0.125f - ((const float*)&kn0)[r]*0.0625f;
            hh[4+r] = s1[r]*0.125f - ((const float*)&kn1)[r]*0.0625f;
        }
        float pmax = hh[0];
#pragma unroll
        for (int r = 1; r < 8; r++) pmax = fmaxf(pmax, hh[r]);
        pmax = fmaxf(pmax, __shfl_xor(pmax, 16, 64));
        pmax = fmaxf(pmax, __shfl_xor(pmax, 32, 64));
        if (__any(pmax > mrun + 8.0f)) {
            float mnew = fmaxf(mrun, pmax);
            float osc = __expf(mrun - mnew);
            mrun = mnew;
            lrun *= osc;
            float osc_pv[4];
#pragma unroll
            for (int r = 0; r < 4; r++) osc_pv[r] = __shfl(osc, l4*4 + r, 64);
#pragma unroll
            for (int et = 0; et < 16; et++) {
                O[et][0] *= osc_pv[0]; O[et][1] *= osc_pv[1];
                O[et][2] *= osc_pv[2]; O[et][3] *= osc_pv[3];
            }
        }
        float p[8], ls = 0.f;
#pragma unroll
        for (int r = 0; r < 8; r++) { p[r] = __expf(hh[r] - mrun); ls += p[r]; }
        ls += __shfl_xor(ls, 16, 64);
        ls += __shfl_xor(ls, 32, 64);
        lrun += ls;
        // pack P hi/lo into PV A-fragments (reg order == pi-slot order)
        bf16x8 pah, pal;
        {
            union { unsigned int u[4]; bf16x8 v; } ch, cl;
#pragma unroll
            for (int i = 0; i < 4; i++) {
                unsigned short h0 = f2bf(p[2*i]),   h1 = f2bf(p[2*i+1]);
                unsigned short l0 = f2bf(p[2*i]   - bf2f(h0));
                unsigned short l1 = f2bf(p[2*i+1] - bf2f(h1));
                ch.u[i] = (unsigned int)h0 | ((unsigned int)h1 << 16);
                cl.u[i] = (unsigned int)l0 | ((unsigned int)l1 << 16);
            }
            pah = ch.v; pal = cl.v;
        }

        __syncthreads();   // B1: V(t) visible; K(t+1) drained

        // ---- 7. issue V(t+1) loads (latency hidden under PV) ----
#pragma unroll
        for (int r = 0; r < 8; r++) {
            int arr = r >> 2;
            int e = (r & 3)*128 + (tid >> 2);
            const unsigned short* src = (arr ? xTlo : xThi) + ((size_t)(b*E_ + e))*L_ + jn + jc*8;
            vreg[r] = *reinterpret_cast<const uint4*>(src);
        }
        // ---- 8. PV: O[16i][e-half 256] += P @ V, 3-MFMA split ----
#pragma unroll
        for (int et = 0; et < 16; et++) {
            int vo = (((h*16 + et)*16 + l15))*64 + l4*16;
            vo ^= ((vo >> 7) & 7) << 4;
            bf16x8 vh = *reinterpret_cast<const bf16x8*>(vh_b + vo);
            bf16x8 vl = *reinterpret_cast<const bf16x8*>(vl_b + vo);
            O[et] = __builtin_amdgcn_mfma_f32_16x16x32_bf16(pah, vh, O[et], 0, 0, 0);
            O[et] = __builtin_amdgcn_mfma_f32_16x16x32_bf16(pal, vh, O[et], 0, 0, 0);
            O[et] = __builtin_amdgcn_mfma_f32_16x16x32_bf16(pah, vl, O[et], 0, 0, 0);
        }

        __syncthreads();   // B2: PV done; V(t+1)/K(t+1) loads drained
        cur ^= 1;
    }

    // ---- epilogue: normalize + store ybar bf16 ----
    float inv = 1.f / lrun;
    float inv_pv[4];
#pragma unroll
    for (int r = 0; r < 4; r++) inv_pv[r] = __shfl(inv, l4*4 + r, 64);
#pragma unroll
    for (int r = 0; r < 4; r++) {
        int row = i0 + rg*16 + l4*4 + r;
        size_t base = (bkL + row)*E_ + h*256 + l15;
#pragma unroll
        for (int et = 0; et < 16; et++)
            ybar[base + et*16] = f2bf(O[et][r] * inv_pv[r]);
    }
}

// ---------------- K4: per-head combine GEMM + bias2, MFMA 2-split B ----------
// per (b,k): C[2048][512] = ybar_bf16 @ (Whi + Wlo); 128x128 tile, 4 waves 2x2.
__global__ __launch_bounds__(256) void combine_kernel(
    const unsigned short* __restrict__ ybar, const unsigned short* __restrict__ whiT,
    const unsigned short* __restrict__ wloT, const float* __restrict__ bias2W,
    float* __restrict__ out)
{
    __shared__ unsigned short A_s[128][40];    // 80 B rows (pad: 2-way banks)
    __shared__ unsigned short Bh_s[128][40];   // [f][e]
    __shared__ unsigned short Bl_s[128][40];

    const int tid = threadIdx.x;
    const int w = tid >> 6, lane = tid & 63;
    const int wm = w >> 1, wn = w & 1;
    const int l15 = lane & 15, l4 = lane >> 4;
    const int m0 = blockIdx.x * 128;
    const int n0 = blockIdx.y * 128;
    const int bk = blockIdx.z;
    const int k = bk & 3, b = bk >> 2;
    const size_t abase = (size_t)bk * L_ * E_;
    const size_t wbase = (size_t)k * E_ * E_;

    f32x4 acc[4][4];
#pragma unroll
    for (int i = 0; i < 4; i++)
#pragma unroll
        for (int j = 0; j < 4; j++) acc[i][j] = (f32x4){0.f,0.f,0.f,0.f};

    for (int e0 = 0; e0 < 512; e0 += 32) {
        __syncthreads();
#pragma unroll
        for (int r = 0; r < 2; r++) {
            int idx = tid + r*256;
            int row = idx >> 2, c = idx & 3;
            *reinterpret_cast<uint4*>(&A_s[row][c*8]) =
                *reinterpret_cast<const uint4*>(&ybar[abase + (size_t)(m0 + row)*E_ + e0 + c*8]);
            *reinterpret_cast<uint4*>(&Bh_s[row][c*8]) =
                *reinterpret_cast<const uint4*>(&whiT[wbase + (size_t)(n0 + row)*E_ + e0 + c*8]);
            *reinterpret_cast<uint4*>(&Bl_s[row][c*8]) =
                *reinterpret_cast<const uint4*>(&wloT[wbase + (size_t)(n0 + row)*E_ + e0 + c*8]);
        }
        __syncthreads();

        bf16x8 a[4], bh[4], bl[4];
#pragma unroll
        for (int mt = 0; mt < 4; mt++)
            a[mt] = *reinterpret_cast<const bf16x8*>(&A_s[wm*64 + mt*16 + l15][l4*8]);
#pragma unroll
        for (int ft = 0; ft < 4; ft++) {
            bh[ft] = *reinterpret_cast<const bf16x8*>(&Bh_s[wn*64 + ft*16 + l15][l4*8]);
            bl[ft] = *reinterpret_cast<const bf16x8*>(&Bl_s[wn*64 + ft*16 + l15][l4*8]);
        }
#pragma unroll
        for (int mt = 0; mt < 4; mt++)
#pragma unroll
            for (int ft = 0; ft < 4; ft++) {
                acc[mt][ft] = __builtin_amdgcn_mfma_f32_16x16x32_bf16(a[mt], bh[ft], acc[mt][ft], 0, 0, 0);
                acc[mt][ft] = __builtin_amdgcn_mfma_f32_16x16x32_bf16(a[mt], bl[ft], acc[mt][ft], 0, 0, 0);
            }
    }

    float bias[4];
#pragma unroll
    for (int ft = 0; ft < 4; ft++)
        bias[ft] = bias2W[(n0 + wn*64 + ft*16 + l15) * NH_ + k];

#pragma unroll
    for (int mt = 0; mt < 4; mt++)
#pragma unroll
        for (int ft = 0; ft < 4; ft++) {
            int f = n0 + wn*64 + ft*16 + l15;
#pragma unroll
            for (int rr = 0; rr < 4; rr++) {
                int i = m0 + wm*64 + mt*16 + l4*4 + rr;
                out[((size_t)(b*L_ + i))*(NH_*E_) + k*E_ + f] = acc[mt][ft][rr] + bias[ft];
            }
        }
}

extern "C" void kernel_launch(void* const* d_in, const int* in_sizes, int n_in,
                              void* d_out, int out_size, void* d_ws, size_t ws_size,
                              hipStream_t stream)
{
    const float* xsa    = (const float*)d_in[0];
    const float* Wq     = (const float*)d_in[1];
    const float* Wk     = (const float*)d_in[2];
    const float* Wv     = (const float*)d_in[3];
    const float* biasW  = (const float*)d_in[4];
    const float* bias2W = (const float*)d_in[5];
    float* out = (float*)d_out;

    unsigned short* ws16 = (unsigned short*)d_ws;
    unsigned short* xqhi  = ws16;                      // 4,194,304
    unsigned short* xqlo  = ws16 + 4194304;
    unsigned short* xkhi  = ws16 + 8388608;
    unsigned short* xklo  = ws16 + 12582912;
    unsigned short* xThi  = ws16 + 16777216;           // 2,097,152
    unsigned short* xTlo  = ws16 + 18874368;
    unsigned short* ybar  = ws16 + 20971520;           // 8,388,608
    float*          knv   = (float*)(ws16 + 29360128); // 16,384 floats
    unsigned short* wvhiT = ws16 + 29392896;           // 1,048,576
    unsigned short* wvloT = ws16 + 30441472;           // 1,048,576 (end ~60.1 MiB)

    proj_kernel<<<dim3(32, 16), 256, 0, stream>>>(xsa, Wq, Wk, biasW, xqhi, xqlo, xkhi, xklo);
    trans_kernel<<<dim3(32, 8, 2), 256, 0, stream>>>(xsa, xThi, xTlo);
    wsplit_kernel<<<dim3(8, 8, 4), 256, 0, stream>>>(Wv, wvhiT, wvloT);
    kn_kernel<<<dim3(4096), 256, 0, stream>>>(xkhi, xklo, knv);
    attn_kernel<<<dim3(32, 8), 512, 0, stream>>>(xqhi, xqlo, xkhi, xklo, xThi, xTlo, knv, ybar);
    combine_kernel<<<dim3(16, 4, 8), 256, 0, stream>>>(ybar, wvhiT, wvloT, bias2W, out);
}